// Round 1
// baseline (900.728 us; speedup 1.0000x reference)
//
#include <hip/hip_runtime.h>
#include <hip/hip_bf16.h>
#include <string.h>

#define NN 50000
#define NE 800000
#define DIN 128
#define DH 256
#define NG 64
#define PSPLIT 32

typedef short bf16x8 __attribute__((ext_vector_type(8)));
typedef float f32x4 __attribute__((ext_vector_type(4)));

__device__ __forceinline__ float bf2f(__hip_bfloat16 v) { return __bfloat162float(v); }
__device__ __forceinline__ float bfbits(unsigned int lo16) {
  unsigned int u = lo16 << 16;
  float f;
  memcpy(&f, &u, 4);
  return f;
}
__device__ __forceinline__ unsigned int packbf2(float x, float y) {
  __hip_bfloat16 bx = __float2bfloat16(x), by = __float2bfloat16(y);
  unsigned short ux, uy;
  memcpy(&ux, &bx, 2);
  memcpy(&uy, &by, 2);
  return (unsigned int)ux | ((unsigned int)uy << 16);
}

// flag-driven generic accessors: fbf=1 -> floats stored as bf16; i64=1 -> ints stored as int64
__device__ __forceinline__ float loadF(const void* p, long i, int fbf) {
  return fbf ? bf2f(((const __hip_bfloat16*)p)[i]) : ((const float*)p)[i];
}
__device__ __forceinline__ void storeF(void* p, long i, float v, int fbf) {
  if (fbf) ((__hip_bfloat16*)p)[i] = __float2bfloat16(v);
  else ((float*)p)[i] = v;
}
__device__ __forceinline__ int loadI(const void* p, long i, int i64) {
  return i64 ? (int)((const long long*)p)[i] : ((const int*)p)[i];
}

__global__ void k_detect(const void* x, const void* ei, int* flags) {
  __shared__ int s_f32sig, s_i32sig;
  if (threadIdx.x == 0) { s_f32sig = 0; s_i32sig = 0; }
  __syncthreads();
  int t = threadIdx.x;
  const unsigned short* u = (const unsigned short*)x;
  int f = 0;
  for (int i = 2 * t; i < 8192; i += 512) if (u[i] >= 0x4000) f = 1;
  const unsigned int* w = (const unsigned int*)ei;
  int g = 0;
  for (int i = 2 * t + 1; i < 8192; i += 512) if (w[i] != 0u) g = 1;
  if (f) atomicOr(&s_f32sig, 1);
  if (g) atomicOr(&s_i32sig, 1);
  __syncthreads();
  if (t == 0) { flags[0] = s_f32sig ? 0 : 1; flags[1] = s_i32sig ? 0 : 1; }
}

__global__ void k_zero(int* __restrict__ p, int n) {
  int i = blockIdx.x * blockDim.x + threadIdx.x;
  int stride = gridDim.x * blockDim.x;
  for (; i < n; i += stride) p[i] = 0;
}

// fused colsum + bf16 conversion, vectorized: 16 threads/row, uint4 (8 bf16) per thread.
// block 256 = 16 rows x 16 col-groups; per-thread 8-col f32 partials -> LDS -> 128 atomics.
__global__ __launch_bounds__(256) void k_prep(
    const void* __restrict__ x, __hip_bfloat16* __restrict__ xb,
    float* __restrict__ colsum, const int* __restrict__ flags) {
  int fbf = flags[0];
  int t = threadIdx.x;
  int lane16 = t & 15;   // col group: cols [8*lane16, 8*lane16+8)
  int rowoff = t >> 4;   // 0..15
  float acc[8] = {};
  for (int r = blockIdx.x * 16 + rowoff; r < NN; r += gridDim.x * 16) {
    uint4 o;
    if (fbf) {
      uint4 v = ((const uint4*)x)[(long)r * 16 + lane16];
      acc[0] += bfbits(v.x & 0xffffu); acc[1] += bfbits(v.x >> 16);
      acc[2] += bfbits(v.y & 0xffffu); acc[3] += bfbits(v.y >> 16);
      acc[4] += bfbits(v.z & 0xffffu); acc[5] += bfbits(v.z >> 16);
      acc[6] += bfbits(v.w & 0xffffu); acc[7] += bfbits(v.w >> 16);
      o = v;  // already bf16 bits
    } else {
      float4 a = ((const float4*)x)[(long)r * 32 + lane16 * 2];
      float4 b = ((const float4*)x)[(long)r * 32 + lane16 * 2 + 1];
      acc[0] += a.x; acc[1] += a.y; acc[2] += a.z; acc[3] += a.w;
      acc[4] += b.x; acc[5] += b.y; acc[6] += b.z; acc[7] += b.w;
      o.x = packbf2(a.x, a.y); o.y = packbf2(a.z, a.w);
      o.z = packbf2(b.x, b.y); o.w = packbf2(b.z, b.w);
    }
    ((uint4*)xb)[(long)r * 16 + lane16] = o;
  }
  __shared__ float s[16][DIN];
#pragma unroll
  for (int k = 0; k < 8; ++k) s[rowoff][lane16 * 8 + k] = acc[k];
  __syncthreads();
  if (t < DIN) {
    float v = 0.f;
#pragma unroll
    for (int ro = 0; ro < 16; ++ro) v += s[ro][t];
    atomicAdd(&colsum[t], v);
  }
}

__global__ void k_handcrafted(const float* __restrict__ colsum, void* __restrict__ out,
                              const int* __restrict__ flags) {
  __shared__ float s[DIN];
  int fbf = flags[0];
  int t = threadIdx.x;
  s[t] = colsum[t];
  __syncthreads();
  for (int off = DIN / 2; off > 0; off >>= 1) {
    if (t < off) s[t] += s[t + off];
    __syncthreads();
  }
  float g = s[0];
  storeF(out, NG * DH + t, colsum[t] / g, fbf);
  if (t == 0) storeF(out, NG * DH + DIN, logf(g), fbf);
}

// pack weights into MFMA b-frag order:
// pack[m*K*DH + ((ct*KS + ks)*64 + l)*8 + j] = W_m[(ks*32 + (l>>4)*8 + j)*DH + ct*16 + (l&15)]
__global__ void k_pack_w(const void* __restrict__ Wrel, const void* __restrict__ Wroot,
                         const void* __restrict__ bias, __hip_bfloat16* __restrict__ pack,
                         float* __restrict__ biasf, const int* __restrict__ flags, int K) {
  int fbf = flags[0];
  int KS = K >> 5;
  int total = 2 * K * DH;
  int i = blockIdx.x * blockDim.x + threadIdx.x;
  int stride = gridDim.x * blockDim.x;
  for (int p = i; p < total; p += stride) {
    int m = p / (K * DH);
    int r = p % (K * DH);
    int j = r & 7;
    int l = (r >> 3) & 63;
    int q2 = r >> 9;       // ct*KS + ks
    int ks = q2 % KS;
    int ct = q2 / KS;
    int kk = ks * 32 + (l >> 4) * 8 + j;
    int col = ct * 16 + (l & 15);
    const void* W = m ? Wroot : Wrel;
    pack[p] = __float2bfloat16(loadF(W, (long)kk * DH + col, fbf));
  }
  if (i < DH) biasf[i] = loadF(bias, i, fbf);
}

// ---------- CSR build ----------
__global__ void k_deg(const void* __restrict__ ei, int* __restrict__ cnt,
                      const int* __restrict__ flags) {
  int i64 = flags[1];
  int e = blockIdx.x * blockDim.x + threadIdx.x;
  int stride = gridDim.x * blockDim.x;
  for (; e < NE; e += stride) {
    int d = loadI(ei, (long)NE + e, i64);
    d = min(max(d, 0), NN - 1);
    atomicAdd(&cnt[d], 1);
  }
}

#define SCAN_B 256
__global__ void k_scan1(const int* __restrict__ cnt, int* __restrict__ rowptr,
                        int* __restrict__ bsum) {
  __shared__ int s[SCAN_B];
  int b = blockIdx.x, t = threadIdx.x;
  int i = b * SCAN_B + t;
  int v = (i < NN) ? cnt[i] : 0;
  s[t] = v;
  __syncthreads();
  for (int off = 1; off < SCAN_B; off <<= 1) {
    int xv = (t >= off) ? s[t - off] : 0;
    __syncthreads();
    s[t] += xv;
    __syncthreads();
  }
  if (i < NN) rowptr[i] = s[t] - v;
  if (t == SCAN_B - 1) bsum[b] = s[t];
}

__global__ void k_scan2(int* __restrict__ bsum, int nb) {
  __shared__ int s[SCAN_B];
  int t = threadIdx.x;
  int v = (t < nb) ? bsum[t] : 0;
  s[t] = v;
  __syncthreads();
  for (int off = 1; off < SCAN_B; off <<= 1) {
    int xv = (t >= off) ? s[t - off] : 0;
    __syncthreads();
    s[t] += xv;
    __syncthreads();
  }
  if (t < nb) bsum[t] = s[t] - v;  // exclusive
}

__global__ void k_scan3(int* __restrict__ rowptr, const int* __restrict__ bsum) {
  int i = blockIdx.x * blockDim.x + threadIdx.x;
  int stride = gridDim.x * blockDim.x;
  for (; i < NN; i += stride) rowptr[i] += bsum[i >> 8];
  if (blockIdx.x == 0 && threadIdx.x == 0) rowptr[NN] = NE;
}

__global__ void k_fill(const void* __restrict__ ei, const int* __restrict__ rowptr,
                       int* __restrict__ cur, int* __restrict__ srcs,
                       const int* __restrict__ flags) {
  int i64 = flags[1];
  int e = blockIdx.x * blockDim.x + threadIdx.x;
  int stride = gridDim.x * blockDim.x;
  for (; e < NE; e += stride) {
    int s = loadI(ei, e, i64);
    int d = loadI(ei, (long)NE + e, i64);
    s = min(max(s, 0), NN - 1);
    d = min(max(d, 0), NN - 1);
    int p = atomicAdd(&cur[d], 1);
    srcs[rowptr[d] + p] = s;
  }
}

// ---------- XCD-sharded gathers ----------
// slice = blockIdx.x % 8 maps to XCD (round-robin dispatch): each XCD only touches
// a 32-col (D=256: 3.2MB) / 16-col (D=128: 1.6MB) column slice of h -> L2-resident.
// Block = 4 waves x 4 nodes each = 16 nodes/block; 3125 node-blocks x 8 slices.
#define GNB ((NN + 15) / 16)

// D=256: 8 slices x 32 cols (16 uints = 64B per row). Wave: 4 edge-groups of 16 lanes.
__global__ __launch_bounds__(256) void k_gather256x(
    const int* __restrict__ rowptr, const int* __restrict__ srcs,
    const __hip_bfloat16* __restrict__ h, __hip_bfloat16* __restrict__ agg) {
  int bid = blockIdx.x;
  int s = bid & 7;        // slice / XCD tag
  int nb = bid >> 3;      // node block (16 nodes)
  int wave = threadIdx.x >> 6;
  int lane = threadIdx.x & 63;
  int g = lane >> 4;      // edge group 0..3
  int c = lane & 15;      // uint within 64B slice
  const unsigned int* h2 = (const unsigned int*)h;  // 128 uints per row
  unsigned int* agg2 = (unsigned int*)agg;
  int colofs = s * 16 + c;
#pragma unroll
  for (int nw = 0; nw < 4; ++nw) {
    int node = nb * 16 + wave * 4 + nw;
    if (node >= NN) break;
    int beg = rowptr[node], end = rowptr[node + 1];
    float a0 = 0.f, a1 = 0.f;
    int i = beg + g;
    for (; i + 12 < end; i += 16) {
      int s0 = __builtin_nontemporal_load(&srcs[i]);
      int s1 = __builtin_nontemporal_load(&srcs[i + 4]);
      int s2 = __builtin_nontemporal_load(&srcs[i + 8]);
      int s3 = __builtin_nontemporal_load(&srcs[i + 12]);
      unsigned v0 = h2[(long)s0 * 128 + colofs];
      unsigned v1 = h2[(long)s1 * 128 + colofs];
      unsigned v2 = h2[(long)s2 * 128 + colofs];
      unsigned v3 = h2[(long)s3 * 128 + colofs];
      a0 += bfbits(v0 & 0xffffu) + bfbits(v1 & 0xffffu) +
            bfbits(v2 & 0xffffu) + bfbits(v3 & 0xffffu);
      a1 += bfbits(v0 >> 16) + bfbits(v1 >> 16) + bfbits(v2 >> 16) + bfbits(v3 >> 16);
    }
    for (; i < end; i += 4) {
      int s0 = __builtin_nontemporal_load(&srcs[i]);
      unsigned v0 = h2[(long)s0 * 128 + colofs];
      a0 += bfbits(v0 & 0xffffu);
      a1 += bfbits(v0 >> 16);
    }
    a0 += __shfl_xor(a0, 16); a0 += __shfl_xor(a0, 32);
    a1 += __shfl_xor(a1, 16); a1 += __shfl_xor(a1, 32);
    if (g == 0)
      __builtin_nontemporal_store(packbf2(a0, a1), &agg2[(long)node * 128 + colofs]);
  }
}

// D=128: 8 slices x 16 cols (8 uints = 32B per row). Wave: 8 edge-groups of 8 lanes.
__global__ __launch_bounds__(256) void k_gather128x(
    const int* __restrict__ rowptr, const int* __restrict__ srcs,
    const __hip_bfloat16* __restrict__ h, __hip_bfloat16* __restrict__ agg) {
  int bid = blockIdx.x;
  int s = bid & 7;        // slice / XCD tag
  int nb = bid >> 3;      // node block (16 nodes)
  int wave = threadIdx.x >> 6;
  int lane = threadIdx.x & 63;
  int g = lane >> 3;      // edge group 0..7
  int c = lane & 7;       // uint within 32B slice
  const unsigned int* h2 = (const unsigned int*)h;  // 64 uints per row
  unsigned int* agg2 = (unsigned int*)agg;
  int colofs = s * 8 + c;
#pragma unroll
  for (int nw = 0; nw < 4; ++nw) {
    int node = nb * 16 + wave * 4 + nw;
    if (node >= NN) break;
    int beg = rowptr[node], end = rowptr[node + 1];
    float a0 = 0.f, a1 = 0.f;
    int i = beg + g;
    for (; i + 8 < end; i += 16) {
      int s0 = __builtin_nontemporal_load(&srcs[i]);
      int s1 = __builtin_nontemporal_load(&srcs[i + 8]);
      unsigned v0 = h2[(long)s0 * 64 + colofs];
      unsigned v1 = h2[(long)s1 * 64 + colofs];
      a0 += bfbits(v0 & 0xffffu) + bfbits(v1 & 0xffffu);
      a1 += bfbits(v0 >> 16) + bfbits(v1 >> 16);
    }
    for (; i < end; i += 8) {
      int s0 = __builtin_nontemporal_load(&srcs[i]);
      unsigned v0 = h2[(long)s0 * 64 + colofs];
      a0 += bfbits(v0 & 0xffffu);
      a1 += bfbits(v0 >> 16);
    }
    a0 += __shfl_xor(a0, 8); a0 += __shfl_xor(a0, 16); a0 += __shfl_xor(a0, 32);
    a1 += __shfl_xor(a1, 8); a1 += __shfl_xor(a1, 16); a1 += __shfl_xor(a1, 32);
    if (g == 0)
      __builtin_nontemporal_store(packbf2(a0, a1), &agg2[(long)node * 64 + colofs]);
  }
}

// out[n][:] = relu(A1[n][:] @ Wrel + A2[n][:] @ Wroot + bias)
// block = 32 rows x 256 cols, 4 waves; wave w = 32x64 tile (mt=2, ct=4), full K unrolled.
template <int K>
__global__ __launch_bounds__(256, 4) void k_gemm(
    const __hip_bfloat16* __restrict__ A1, const __hip_bfloat16* __restrict__ A2,
    const __hip_bfloat16* __restrict__ Wpack, const float* __restrict__ bias,
    __hip_bfloat16* __restrict__ out) {
  constexpr int KS = K >> 5;
  int lane = threadIdx.x & 63;
  int wave = threadIdx.x >> 6;
  int m15 = lane & 15;
  int q = lane >> 4;
  int row0 = blockIdx.x * 32;
  const short* A1s = (const short*)A1;
  const short* A2s = (const short*)A2;
  const short* Wp = (const short*)Wpack;
  const int wrootOfs = K * DH;  // elems: second packed matrix
  f32x4 acc[2][4] = {};
#pragma unroll
  for (int ks = 0; ks < KS; ++ks) {
    int kofs = ks * 32 + q * 8;
    bf16x8 a1[2], a2[2], b1[4], b2[4];
#pragma unroll
    for (int mt = 0; mt < 2; ++mt) {
      int r = row0 + mt * 16 + m15;
      if (r > NN - 1) r = NN - 1;
      a1[mt] = *(const bf16x8*)(A1s + r * K + kofs);
      a2[mt] = *(const bf16x8*)(A2s + r * K + kofs);
    }
#pragma unroll
    for (int ct = 0; ct < 4; ++ct) {
      int gct = wave * 4 + ct;
      const short* base = Wp + ((gct * KS + ks) * 64 + lane) * 8;
      b1[ct] = *(const bf16x8*)(base);
      b2[ct] = *(const bf16x8*)(base + wrootOfs);
    }
#pragma unroll
    for (int mt = 0; mt < 2; ++mt)
#pragma unroll
      for (int ct = 0; ct < 4; ++ct) {
        acc[mt][ct] = __builtin_amdgcn_mfma_f32_16x16x32_bf16(a1[mt], b1[ct], acc[mt][ct], 0, 0, 0);
        acc[mt][ct] = __builtin_amdgcn_mfma_f32_16x16x32_bf16(a2[mt], b2[ct], acc[mt][ct], 0, 0, 0);
      }
  }
#pragma unroll
  for (int mt = 0; mt < 2; ++mt)
#pragma unroll
    for (int ct = 0; ct < 4; ++ct) {
      int col = (wave * 4 + ct) * 16 + m15;
      float bv = bias[col];
#pragma unroll
      for (int r = 0; r < 4; ++r) {
        int row = row0 + mt * 16 + q * 4 + r;
        if (row < NN) {
          float v = acc[mt][ct][r] + bv;
          out[row * DH + col] = __float2bfloat16(fmaxf(v, 0.f));
        }
      }
    }
}

// ---------- pooling (batch is sorted -> segment bounds, no big atomics) ----------
__global__ void k_bounds(const void* __restrict__ batch, int* __restrict__ gstart,
                         int* __restrict__ gend, const int* __restrict__ flags) {
  int i64 = flags[1];
  int n = blockIdx.x * blockDim.x + threadIdx.x;
  if (n >= NN) return;
  int b = min(max(loadI(batch, n, i64), 0), NG - 1);
  int bp = (n == 0) ? -1 : min(max(loadI(batch, n - 1, i64), 0), NG - 1);
  if (b != bp) gstart[b] = n;
  int bn = (n == NN - 1) ? -1 : min(max(loadI(batch, n + 1, i64), 0), NG - 1);
  if (b != bn) gend[b] = n + 1;
}

// grid (NG, PSPLIT), block 128: each block partial-sums a slice of the graph's rows
__global__ void k_poolpart(const int* __restrict__ gstart, const int* __restrict__ gend,
                           const __hip_bfloat16* __restrict__ h, float* __restrict__ pooled) {
  int g = blockIdx.x;
  int p = blockIdx.y;
  int j = threadIdx.x;  // 0..127, 2 cols each
  int s = gstart[g], e = gend[g];
  int len = e - s;
  if (len <= 0) return;
  int chunk = (len + PSPLIT - 1) / PSPLIT;
  int rs = s + p * chunk;
  int re = min(rs + chunk, e);
  if (rs >= re) return;
  const unsigned int* h2 = (const unsigned int*)h;  // 128 uints per row
  float a0 = 0.f, a1 = 0.f;
  for (int r = rs; r < re; ++r) {
    unsigned int v = h2[(long)r * 128 + j];
    a0 += bfbits(v & 0xffffu);
    a1 += bfbits(v >> 16);
  }
  atomicAdd(&pooled[g * DH + 2 * j], a0);
  atomicAdd(&pooled[g * DH + 2 * j + 1], a1);
}

__global__ void k_poolfin(const int* __restrict__ gstart, const int* __restrict__ gend,
                          const float* __restrict__ pooled, void* __restrict__ out,
                          const int* __restrict__ flags) {
  int fbf = flags[0];
  int g = blockIdx.x;
  int j = threadIdx.x;
  float cnt = fmaxf((float)(gend[g] - gstart[g]), 1.0f);
  storeF(out, (long)g * DH + j, pooled[g * DH + j] / cnt, fbf);
}

extern "C" void kernel_launch(void* const* d_in, const int* in_sizes, int n_in,
                              void* d_out, int out_size, void* d_ws, size_t ws_size,
                              hipStream_t stream) {
  const void* x = d_in[0];
  const void* ei = d_in[1];
  const void* batch = d_in[2];
  const void* W1r = d_in[3];
  const void* W1o = d_in[4];
  const void* b1 = d_in[5];
  const void* W2r = d_in[6];
  const void* W2o = d_in[7];
  const void* b2 = d_in[8];
  void* out = d_out;

  // ---- workspace layout (256B-aligned chunks) ----
  char* w = (char*)d_ws;
  auto alloc = [&](size_t bytes) -> char* {
    char* p = w;
    w += (bytes + 255) & ~(size_t)255;
    return p;
  };
  int* flags = (int*)alloc(64);
  // contiguous zero region: cnt, cur, colsum, gstart, gend, pooled
  const int zero_n = NN + NN + DIN + NG + NG + NG * DH;
  int* zreg = (int*)alloc((size_t)zero_n * 4);
  int* cnt = zreg;
  int* cur = cnt + NN;
  float* colsum = (float*)(cur + NN);
  int* gstart = (int*)(colsum + DIN);
  int* gend = gstart + NG;
  float* pooled = (float*)(gend + NG);
  int* rowptr = (int*)alloc((NN + 1) * 4);
  int* bsum = (int*)alloc(SCAN_B * 4);
  int* srcs = (int*)alloc((size_t)NE * 4);
  __hip_bfloat16* xb = (__hip_bfloat16*)alloc((size_t)NN * DIN * 2);
  __hip_bfloat16* aggb = (__hip_bfloat16*)alloc((size_t)NN * DH * 2);
  __hip_bfloat16* hA = (__hip_bfloat16*)alloc((size_t)NN * DH * 2);
  __hip_bfloat16* hB = (__hip_bfloat16*)alloc((size_t)NN * DH * 2);
  __hip_bfloat16* wp1 = (__hip_bfloat16*)alloc((size_t)2 * DIN * DH * 2);
  __hip_bfloat16* wp2 = (__hip_bfloat16*)alloc((size_t)2 * DH * DH * 2);
  float* b1f = (float*)alloc(DH * 4);
  float* b2f = (float*)alloc(DH * 4);

  const int nblk = (NN + SCAN_B - 1) / SCAN_B;       // 196
  const int gemm_grid = (NN + 31) / 32;              // 1563
  const int gat_grid = 8 * GNB;                      // 8 slices x 3125 node-blocks

  k_detect<<<1, 256, 0, stream>>>(x, ei, flags);
  k_zero<<<512, 256, 0, stream>>>(zreg, zero_n);

  // weight packing + fused colsum/convert + handcrafted head
  k_pack_w<<<64, 256, 0, stream>>>(W1r, W1o, b1, wp1, b1f, flags, DIN);
  k_pack_w<<<128, 256, 0, stream>>>(W2r, W2o, b2, wp2, b2f, flags, DH);
  k_prep<<<1024, 256, 0, stream>>>(x, xb, colsum, flags);
  k_handcrafted<<<1, 128, 0, stream>>>(colsum, out, flags);

  // CSR build (once; reused by all 3 layers)
  k_deg<<<1024, 256, 0, stream>>>(ei, cnt, flags);
  k_scan1<<<nblk, SCAN_B, 0, stream>>>(cnt, rowptr, bsum);
  k_scan2<<<1, SCAN_B, 0, stream>>>(bsum, nblk);
  k_scan3<<<256, 256, 0, stream>>>(rowptr, bsum);
  k_fill<<<1024, 256, 0, stream>>>(ei, rowptr, cur, srcs, flags);

  // layer 1 (K = 128): xb -> hA
  k_gather128x<<<gat_grid, 256, 0, stream>>>(rowptr, srcs, xb, aggb);
  k_gemm<DIN><<<gemm_grid, 256, 0, stream>>>(aggb, xb, wp1, b1f, hA);
  // layer 2 (K = 256): hA -> hB (ping-pong, no aliasing)
  k_gather256x<<<gat_grid, 256, 0, stream>>>(rowptr, srcs, hA, aggb);
  k_gemm<DH><<<gemm_grid, 256, 0, stream>>>(aggb, hA, wp2, b2f, hB);
  // layer 3 (K = 256, shared weights): hB -> hA
  k_gather256x<<<gat_grid, 256, 0, stream>>>(rowptr, srcs, hB, aggb);
  k_gemm<DH><<<gemm_grid, 256, 0, stream>>>(aggb, hB, wp2, b2f, hA);

  // mean pool: segment bounds (batch sorted) + split partial sums + finalize
  k_bounds<<<nblk, 256, 0, stream>>>(batch, gstart, gend, flags);
  k_poolpart<<<dim3(NG, PSPLIT), 128, 0, stream>>>(gstart, gend, hA, pooled);
  k_poolfin<<<NG, DH, 0, stream>>>(gstart, gend, pooled, out, flags);
}

// Round 3
// 679.656 us; speedup vs baseline: 1.3253x; 1.3253x over previous
//
#include <hip/hip_runtime.h>
#include <hip/hip_bf16.h>
#include <string.h>

#define NN 50000
#define NE 800000
#define DIN 128
#define DH 256
#define NG 64
#define PSPLIT 32

typedef short bf16x8 __attribute__((ext_vector_type(8)));
typedef float f32x4 __attribute__((ext_vector_type(4)));
typedef unsigned int u32x2 __attribute__((ext_vector_type(2)));

__device__ __forceinline__ float bf2f(__hip_bfloat16 v) { return __bfloat162float(v); }
__device__ __forceinline__ float bfbits(unsigned int lo16) {
  unsigned int u = lo16 << 16;
  float f;
  memcpy(&f, &u, 4);
  return f;
}
__device__ __forceinline__ unsigned int packbf2(float x, float y) {
  __hip_bfloat16 bx = __float2bfloat16(x), by = __float2bfloat16(y);
  unsigned short ux, uy;
  memcpy(&ux, &bx, 2);
  memcpy(&uy, &by, 2);
  return (unsigned int)ux | ((unsigned int)uy << 16);
}

// flag-driven generic accessors: fbf=1 -> floats stored as bf16; i64=1 -> ints stored as int64
__device__ __forceinline__ float loadF(const void* p, long i, int fbf) {
  return fbf ? bf2f(((const __hip_bfloat16*)p)[i]) : ((const float*)p)[i];
}
__device__ __forceinline__ void storeF(void* p, long i, float v, int fbf) {
  if (fbf) ((__hip_bfloat16*)p)[i] = __float2bfloat16(v);
  else ((float*)p)[i] = v;
}
__device__ __forceinline__ int loadI(const void* p, long i, int i64) {
  return i64 ? (int)((const long long*)p)[i] : ((const int*)p)[i];
}

__global__ void k_detect(const void* x, const void* ei, int* flags) {
  __shared__ int s_f32sig, s_i32sig;
  if (threadIdx.x == 0) { s_f32sig = 0; s_i32sig = 0; }
  __syncthreads();
  int t = threadIdx.x;
  const unsigned short* u = (const unsigned short*)x;
  int f = 0;
  for (int i = 2 * t; i < 8192; i += 512) if (u[i] >= 0x4000) f = 1;
  const unsigned int* w = (const unsigned int*)ei;
  int g = 0;
  for (int i = 2 * t + 1; i < 8192; i += 512) if (w[i] != 0u) g = 1;
  if (f) atomicOr(&s_f32sig, 1);
  if (g) atomicOr(&s_i32sig, 1);
  __syncthreads();
  if (t == 0) { flags[0] = s_f32sig ? 0 : 1; flags[1] = s_i32sig ? 0 : 1; }
}

__global__ void k_zero(int* __restrict__ p, int n) {
  int i = blockIdx.x * blockDim.x + threadIdx.x;
  int stride = gridDim.x * blockDim.x;
  for (; i < n; i += stride) p[i] = 0;
}

// fused colsum + bf16 conversion; output is SLICE-MAJOR xs[4][NN][32cols]
// (64B contiguous per node per slice -> pure L2 lines for the sharded gather).
// block 256 = 16 rows x 16 col-groups; per-thread 8-col f32 partials -> LDS -> 128 atomics.
__global__ __launch_bounds__(256) void k_prep(
    const void* __restrict__ x, __hip_bfloat16* __restrict__ xs,
    float* __restrict__ colsum, const int* __restrict__ flags) {
  int fbf = flags[0];
  int t = threadIdx.x;
  int lane16 = t & 15;   // col group: cols [8*lane16, 8*lane16+8)
  int rowoff = t >> 4;   // 0..15
  float acc[8] = {};
  for (int r = blockIdx.x * 16 + rowoff; r < NN; r += gridDim.x * 16) {
    uint4 o;
    if (fbf) {
      uint4 v = ((const uint4*)x)[(long)r * 16 + lane16];
      acc[0] += bfbits(v.x & 0xffffu); acc[1] += bfbits(v.x >> 16);
      acc[2] += bfbits(v.y & 0xffffu); acc[3] += bfbits(v.y >> 16);
      acc[4] += bfbits(v.z & 0xffffu); acc[5] += bfbits(v.z >> 16);
      acc[6] += bfbits(v.w & 0xffffu); acc[7] += bfbits(v.w >> 16);
      o = v;  // already bf16 bits
    } else {
      float4 a = ((const float4*)x)[(long)r * 32 + lane16 * 2];
      float4 b = ((const float4*)x)[(long)r * 32 + lane16 * 2 + 1];
      acc[0] += a.x; acc[1] += a.y; acc[2] += a.z; acc[3] += a.w;
      acc[4] += b.x; acc[5] += b.y; acc[6] += b.z; acc[7] += b.w;
      o.x = packbf2(a.x, a.y); o.y = packbf2(a.z, a.w);
      o.z = packbf2(b.x, b.y); o.w = packbf2(b.z, b.w);
    }
    // slice-major: slice = lane16>>2 (32 cols), within-slice uint4 = lane16&3
    ((uint4*)xs)[((long)(lane16 >> 2) * NN + r) * 4 + (lane16 & 3)] = o;
  }
  __shared__ float s[16][DIN];
#pragma unroll
  for (int k = 0; k < 8; ++k) s[rowoff][lane16 * 8 + k] = acc[k];
  __syncthreads();
  if (t < DIN) {
    float v = 0.f;
#pragma unroll
    for (int ro = 0; ro < 16; ++ro) v += s[ro][t];
    atomicAdd(&colsum[t], v);
  }
}

__global__ void k_handcrafted(const float* __restrict__ colsum, void* __restrict__ out,
                              const int* __restrict__ flags) {
  __shared__ float s[DIN];
  int fbf = flags[0];
  int t = threadIdx.x;
  s[t] = colsum[t];
  __syncthreads();
  for (int off = DIN / 2; off > 0; off >>= 1) {
    if (t < off) s[t] += s[t + off];
    __syncthreads();
  }
  float g = s[0];
  storeF(out, NG * DH + t, colsum[t] / g, fbf);
  if (t == 0) storeF(out, NG * DH + DIN, logf(g), fbf);
}

// pack weights into MFMA b-frag order:
// pack[m*K*DH + ((ct*KS + ks)*64 + l)*8 + j] = W_m[(ks*32 + (l>>4)*8 + j)*DH + ct*16 + (l&15)]
__global__ void k_pack_w(const void* __restrict__ Wrel, const void* __restrict__ Wroot,
                         const void* __restrict__ bias, __hip_bfloat16* __restrict__ pack,
                         float* __restrict__ biasf, const int* __restrict__ flags, int K) {
  int fbf = flags[0];
  int KS = K >> 5;
  int total = 2 * K * DH;
  int i = blockIdx.x * blockDim.x + threadIdx.x;
  int stride = gridDim.x * blockDim.x;
  for (int p = i; p < total; p += stride) {
    int m = p / (K * DH);
    int r = p % (K * DH);
    int j = r & 7;
    int l = (r >> 3) & 63;
    int q2 = r >> 9;       // ct*KS + ks
    int ks = q2 % KS;
    int ct = q2 / KS;
    int kk = ks * 32 + (l >> 4) * 8 + j;
    int col = ct * 16 + (l & 15);
    const void* W = m ? Wroot : Wrel;
    pack[p] = __float2bfloat16(loadF(W, (long)kk * DH + col, fbf));
  }
  if (i < DH) biasf[i] = loadF(bias, i, fbf);
}

// ---------- CSR build ----------
__global__ void k_deg(const void* __restrict__ ei, int* __restrict__ cnt,
                      const int* __restrict__ flags) {
  int i64 = flags[1];
  int e = blockIdx.x * blockDim.x + threadIdx.x;
  int stride = gridDim.x * blockDim.x;
  for (; e < NE; e += stride) {
    int d = loadI(ei, (long)NE + e, i64);
    d = min(max(d, 0), NN - 1);
    atomicAdd(&cnt[d], 1);
  }
}

#define SCAN_B 256
__global__ void k_scan1(const int* __restrict__ cnt, int* __restrict__ rowptr,
                        int* __restrict__ bsum) {
  __shared__ int s[SCAN_B];
  int b = blockIdx.x, t = threadIdx.x;
  int i = b * SCAN_B + t;
  int v = (i < NN) ? cnt[i] : 0;
  s[t] = v;
  __syncthreads();
  for (int off = 1; off < SCAN_B; off <<= 1) {
    int xv = (t >= off) ? s[t - off] : 0;
    __syncthreads();
    s[t] += xv;
    __syncthreads();
  }
  if (i < NN) rowptr[i] = s[t] - v;
  if (t == SCAN_B - 1) bsum[b] = s[t];
}

__global__ void k_scan2(int* __restrict__ bsum, int nb) {
  __shared__ int s[SCAN_B];
  int t = threadIdx.x;
  int v = (t < nb) ? bsum[t] : 0;
  s[t] = v;
  __syncthreads();
  for (int off = 1; off < SCAN_B; off <<= 1) {
    int xv = (t >= off) ? s[t - off] : 0;
    __syncthreads();
    s[t] += xv;
    __syncthreads();
  }
  if (t < nb) bsum[t] = s[t] - v;  // exclusive
}

__global__ void k_scan3(int* __restrict__ rowptr, const int* __restrict__ bsum) {
  int i = blockIdx.x * blockDim.x + threadIdx.x;
  int stride = gridDim.x * blockDim.x;
  for (; i < NN; i += stride) rowptr[i] += bsum[i >> 8];
  if (blockIdx.x == 0 && threadIdx.x == 0) rowptr[NN] = NE;
}

__global__ void k_fill(const void* __restrict__ ei, const int* __restrict__ rowptr,
                       int* __restrict__ cur, int* __restrict__ srcs,
                       const int* __restrict__ flags) {
  int i64 = flags[1];
  int e = blockIdx.x * blockDim.x + threadIdx.x;
  int stride = gridDim.x * blockDim.x;
  for (; e < NE; e += stride) {
    int s = loadI(ei, e, i64);
    int d = loadI(ei, (long)NE + e, i64);
    s = min(max(s, 0), NN - 1);
    d = min(max(d, 0), NN - 1);
    int p = atomicAdd(&cur[d], 1);
    srcs[rowptr[d] + p] = s;
  }
}

// ---------- XCD-sharded gather over SLICE-MAJOR h ----------
// hs layout: [SL][NN][64B] with SL = K/32 slices of 32 cols. Each slice is a
// contiguous 3.2MB (K=256) / 6.4MB-split-in-halves (K=128) region -> pure 128B
// L2 lines, per-XCD working set <= 3.2MB < 4MiB L2.
// role = blockIdx.x & 7 -> XCD (round-robin dispatch). K=256: role = slice.
// K=128: 4 slices x 2 node-halves (role = slice*2 + half).
// Wave: 8 edge-groups x 8 lanes x u32x2 (64B = full slice row per group).
template <int K>
__global__ __launch_bounds__(256) void k_gathers(
    const int* __restrict__ rowptr, const int* __restrict__ srcs,
    const __hip_bfloat16* __restrict__ hs, __hip_bfloat16* __restrict__ agg) {
  constexpr int SL = K / 32;
  constexpr int HALVES = 8 / SL;
  constexpr int NPH = (NN + HALVES - 1) / HALVES;
  int role = blockIdx.x & 7;
  int nb = blockIdx.x >> 3;
  int s = role / HALVES;
  int half = role % HALVES;
  int wave = threadIdx.x >> 6;
  int lane = threadIdx.x & 63;
  int g = lane >> 3;  // edge group 0..7
  int c = lane & 7;   // u32x2 within 64B slice row
  const u32x2* h2 = (const u32x2*)hs;
  u32x2* agg2 = (u32x2*)agg;
  long sbase = (long)s * NN;
  int nlim = min((half + 1) * NPH, NN);
#pragma unroll
  for (int nw = 0; nw < 4; ++nw) {
    int node = half * NPH + nb * 16 + wave * 4 + nw;
    if (node >= nlim) break;
    int beg = rowptr[node], end = rowptr[node + 1];
    float a0 = 0.f, a1 = 0.f, a2 = 0.f, a3 = 0.f;
    int i = beg + g;
    for (; i + 8 < end; i += 16) {
      int s0 = __builtin_nontemporal_load(&srcs[i]);
      int s1 = __builtin_nontemporal_load(&srcs[i + 8]);
      u32x2 v0 = h2[(sbase + s0) * 8 + c];
      u32x2 v1 = h2[(sbase + s1) * 8 + c];
      a0 += bfbits(v0.x & 0xffffu) + bfbits(v1.x & 0xffffu);
      a1 += bfbits(v0.x >> 16) + bfbits(v1.x >> 16);
      a2 += bfbits(v0.y & 0xffffu) + bfbits(v1.y & 0xffffu);
      a3 += bfbits(v0.y >> 16) + bfbits(v1.y >> 16);
    }
    for (; i < end; i += 8) {
      int s0 = __builtin_nontemporal_load(&srcs[i]);
      u32x2 v0 = h2[(sbase + s0) * 8 + c];
      a0 += bfbits(v0.x & 0xffffu);
      a1 += bfbits(v0.x >> 16);
      a2 += bfbits(v0.y & 0xffffu);
      a3 += bfbits(v0.y >> 16);
    }
    // reduce across the 8 edge-groups (lane bits 3..5)
    a0 += __shfl_xor(a0, 8); a1 += __shfl_xor(a1, 8);
    a2 += __shfl_xor(a2, 8); a3 += __shfl_xor(a3, 8);
    a0 += __shfl_xor(a0, 16); a1 += __shfl_xor(a1, 16);
    a2 += __shfl_xor(a2, 16); a3 += __shfl_xor(a3, 16);
    a0 += __shfl_xor(a0, 32); a1 += __shfl_xor(a1, 32);
    a2 += __shfl_xor(a2, 32); a3 += __shfl_xor(a3, 32);
    if (g == 0) {
      u32x2 o;
      o.x = packbf2(a0, a1);
      o.y = packbf2(a2, a3);
      __builtin_nontemporal_store(o, &agg2[(long)node * (K / 4) + s * 8 + c]);
    }
  }
}

// out[n][:] = relu(A1[n][:] @ Wrel + A2[n][:] @ Wroot + bias)
// A1 node-major (gather output). A2 SLICE-MAJOR [K/32][NN][32cols]: each bf16x8
// fragment (kofs=ks*32+q*8) sits inside slice ks at offset q*8. OUTS=true ->
// write slice-major [8][NN][32cols] (feeds next gather); else node-major (pool).
template <int K, bool OUTS>
__global__ __launch_bounds__(256, 4) void k_gemm(
    const __hip_bfloat16* __restrict__ A1, const __hip_bfloat16* __restrict__ A2,
    const __hip_bfloat16* __restrict__ Wpack, const float* __restrict__ bias,
    __hip_bfloat16* __restrict__ out) {
  constexpr int KS = K >> 5;
  int lane = threadIdx.x & 63;
  int wave = threadIdx.x >> 6;
  int m15 = lane & 15;
  int q = lane >> 4;
  int row0 = blockIdx.x * 32;
  const short* A1s = (const short*)A1;
  const short* A2s = (const short*)A2;
  const short* Wp = (const short*)Wpack;
  const int wrootOfs = K * DH;  // elems: second packed matrix
  f32x4 acc[2][4] = {};
#pragma unroll
  for (int ks = 0; ks < KS; ++ks) {
    int kofs = ks * 32 + q * 8;
    bf16x8 a1[2], a2[2], b1[4], b2[4];
#pragma unroll
    for (int mt = 0; mt < 2; ++mt) {
      int r = row0 + mt * 16 + m15;
      if (r > NN - 1) r = NN - 1;
      a1[mt] = *(const bf16x8*)(A1s + (long)r * K + kofs);
      // slice-major A2: ((ks*NN + r)*32 + q*8)   [valid for K=128 and K=256]
      a2[mt] = *(const bf16x8*)(A2s + ((long)ks * NN + r) * 32 + q * 8);
    }
#pragma unroll
    for (int ct = 0; ct < 4; ++ct) {
      int gct = wave * 4 + ct;
      const short* base = Wp + ((gct * KS + ks) * 64 + lane) * 8;
      b1[ct] = *(const bf16x8*)(base);
      b2[ct] = *(const bf16x8*)(base + wrootOfs);
    }
#pragma unroll
    for (int mt = 0; mt < 2; ++mt)
#pragma unroll
      for (int ct = 0; ct < 4; ++ct) {
        acc[mt][ct] = __builtin_amdgcn_mfma_f32_16x16x32_bf16(a1[mt], b1[ct], acc[mt][ct], 0, 0, 0);
        acc[mt][ct] = __builtin_amdgcn_mfma_f32_16x16x32_bf16(a2[mt], b2[ct], acc[mt][ct], 0, 0, 0);
      }
  }
#pragma unroll
  for (int mt = 0; mt < 2; ++mt)
#pragma unroll
    for (int ct = 0; ct < 4; ++ct) {
      int col = (wave * 4 + ct) * 16 + m15;
      float bv = bias[col];
#pragma unroll
      for (int r = 0; r < 4; ++r) {
        int row = row0 + mt * 16 + q * 4 + r;
        if (row < NN) {
          float v = acc[mt][ct][r] + bv;
          long oidx = OUTS ? (((long)(col >> 5) * NN + row) * 32 + (col & 31))
                           : ((long)row * DH + col);
          out[oidx] = __float2bfloat16(fmaxf(v, 0.f));
        }
      }
    }
}

// ---------- pooling (batch is sorted -> segment bounds, no big atomics) ----------
__global__ void k_bounds(const void* __restrict__ batch, int* __restrict__ gstart,
                         int* __restrict__ gend, const int* __restrict__ flags) {
  int i64 = flags[1];
  int n = blockIdx.x * blockDim.x + threadIdx.x;
  if (n >= NN) return;
  int b = min(max(loadI(batch, n, i64), 0), NG - 1);
  int bp = (n == 0) ? -1 : min(max(loadI(batch, n - 1, i64), 0), NG - 1);
  if (b != bp) gstart[b] = n;
  int bn = (n == NN - 1) ? -1 : min(max(loadI(batch, n + 1, i64), 0), NG - 1);
  if (b != bn) gend[b] = n + 1;
}

// grid (NG, PSPLIT), block 128: each block partial-sums a slice of the graph's rows
__global__ void k_poolpart(const int* __restrict__ gstart, const int* __restrict__ gend,
                           const __hip_bfloat16* __restrict__ h, float* __restrict__ pooled) {
  int g = blockIdx.x;
  int p = blockIdx.y;
  int j = threadIdx.x;  // 0..127, 2 cols each
  int s = gstart[g], e = gend[g];
  int len = e - s;
  if (len <= 0) return;
  int chunk = (len + PSPLIT - 1) / PSPLIT;
  int rs = s + p * chunk;
  int re = min(rs + chunk, e);
  if (rs >= re) return;
  const unsigned int* h2 = (const unsigned int*)h;  // 128 uints per row
  float a0 = 0.f, a1 = 0.f;
  for (int r = rs; r < re; ++r) {
    unsigned int v = h2[(long)r * 128 + j];
    a0 += bfbits(v & 0xffffu);
    a1 += bfbits(v >> 16);
  }
  atomicAdd(&pooled[g * DH + 2 * j], a0);
  atomicAdd(&pooled[g * DH + 2 * j + 1], a1);
}

__global__ void k_poolfin(const int* __restrict__ gstart, const int* __restrict__ gend,
                          const float* __restrict__ pooled, void* __restrict__ out,
                          const int* __restrict__ flags) {
  int fbf = flags[0];
  int g = blockIdx.x;
  int j = threadIdx.x;
  float cnt = fmaxf((float)(gend[g] - gstart[g]), 1.0f);
  storeF(out, (long)g * DH + j, pooled[g * DH + j] / cnt, fbf);
}

extern "C" void kernel_launch(void* const* d_in, const int* in_sizes, int n_in,
                              void* d_out, int out_size, void* d_ws, size_t ws_size,
                              hipStream_t stream) {
  const void* x = d_in[0];
  const void* ei = d_in[1];
  const void* batch = d_in[2];
  const void* W1r = d_in[3];
  const void* W1o = d_in[4];
  const void* b1 = d_in[5];
  const void* W2r = d_in[6];
  const void* W2o = d_in[7];
  const void* b2 = d_in[8];
  void* out = d_out;

  // ---- workspace layout (256B-aligned chunks) ----
  char* w = (char*)d_ws;
  auto alloc = [&](size_t bytes) -> char* {
    char* p = w;
    w += (bytes + 255) & ~(size_t)255;
    return p;
  };
  int* flags = (int*)alloc(64);
  // contiguous zero region: cnt, cur, colsum, gstart, gend, pooled
  const int zero_n = NN + NN + DIN + NG + NG + NG * DH;
  int* zreg = (int*)alloc((size_t)zero_n * 4);
  int* cnt = zreg;
  int* cur = cnt + NN;
  float* colsum = (float*)(cur + NN);
  int* gstart = (int*)(colsum + DIN);
  int* gend = gstart + NG;
  float* pooled = (float*)(gend + NG);
  int* rowptr = (int*)alloc((NN + 1) * 4);
  int* bsum = (int*)alloc(SCAN_B * 4);
  int* srcs = (int*)alloc((size_t)NE * 4);
  __hip_bfloat16* xs = (__hip_bfloat16*)alloc((size_t)NN * DIN * 2);    // slice-major x
  __hip_bfloat16* aggb = (__hip_bfloat16*)alloc((size_t)NN * DH * 2);   // node-major agg
  __hip_bfloat16* h1s = (__hip_bfloat16*)alloc((size_t)NN * DH * 2);    // slice-major h1 / node-major h3
  __hip_bfloat16* h2s = (__hip_bfloat16*)alloc((size_t)NN * DH * 2);    // slice-major h2
  __hip_bfloat16* wp1 = (__hip_bfloat16*)alloc((size_t)2 * DIN * DH * 2);
  __hip_bfloat16* wp2 = (__hip_bfloat16*)alloc((size_t)2 * DH * DH * 2);
  float* b1f = (float*)alloc(DH * 4);
  float* b2f = (float*)alloc(DH * 4);
  __hip_bfloat16* hA = h1s;  // layer-3 node-major output aliases h1s (dead after gemm2)

  const int nblk = (NN + SCAN_B - 1) / SCAN_B;       // 196
  const int gemm_grid = (NN + 31) / 32;              // 1563
  const int g256_grid = 8 * ((NN + 15) / 16);        // 8 roles x 3125
  const int g128_grid = 8 * ((NN / 2 + 15) / 16);    // 8 roles x 1563 (4 slices x 2 halves)

  k_detect<<<1, 256, 0, stream>>>(x, ei, flags);
  k_zero<<<512, 256, 0, stream>>>(zreg, zero_n);

  // weight packing + fused colsum/convert + handcrafted head
  k_pack_w<<<64, 256, 0, stream>>>(W1r, W1o, b1, wp1, b1f, flags, DIN);
  k_pack_w<<<128, 256, 0, stream>>>(W2r, W2o, b2, wp2, b2f, flags, DH);
  k_prep<<<1024, 256, 0, stream>>>(x, xs, colsum, flags);
  k_handcrafted<<<1, 128, 0, stream>>>(colsum, out, flags);

  // CSR build (once; reused by all 3 layers)
  k_deg<<<1024, 256, 0, stream>>>(ei, cnt, flags);
  k_scan1<<<nblk, SCAN_B, 0, stream>>>(cnt, rowptr, bsum);
  k_scan2<<<1, SCAN_B, 0, stream>>>(bsum, nblk);
  k_scan3<<<256, 256, 0, stream>>>(rowptr, bsum);
  k_fill<<<1024, 256, 0, stream>>>(ei, rowptr, cur, srcs, flags);

  // layer 1 (K = 128): xs -> aggb -> h1s (slice-major)
  k_gathers<DIN><<<g128_grid, 256, 0, stream>>>(rowptr, srcs, xs, aggb);
  k_gemm<DIN, true><<<gemm_grid, 256, 0, stream>>>(aggb, xs, wp1, b1f, h1s);
  // layer 2 (K = 256): h1s -> aggb -> h2s (slice-major)
  k_gathers<DH><<<g256_grid, 256, 0, stream>>>(rowptr, srcs, h1s, aggb);
  k_gemm<DH, true><<<gemm_grid, 256, 0, stream>>>(aggb, h1s, wp2, b2f, h2s);
  // layer 3 (K = 256, shared weights): h2s -> aggb -> hA (node-major, for pool)
  k_gathers<DH><<<g256_grid, 256, 0, stream>>>(rowptr, srcs, h2s, aggb);
  k_gemm<DH, false><<<gemm_grid, 256, 0, stream>>>(aggb, h2s, wp2, b2f, hA);

  // mean pool: segment bounds (batch sorted) + split partial sums + finalize
  k_bounds<<<nblk, 256, 0, stream>>>(batch, gstart, gend, flags);
  k_poolpart<<<dim3(NG, PSPLIT), 128, 0, stream>>>(gstart, gend, hA, pooled);
  k_poolfin<<<NG, DH, 0, stream>>>(gstart, gend, pooled, out, flags);
}

// Round 4
// 586.358 us; speedup vs baseline: 1.5361x; 1.1591x over previous
//
#include <hip/hip_runtime.h>
#include <hip/hip_bf16.h>
#include <string.h>

#define NN 50000
#define NE 800000
#define DIN 128
#define DH 256
#define NG 64
#define PSPLIT 32

typedef short bf16x8 __attribute__((ext_vector_type(8)));
typedef float f32x4 __attribute__((ext_vector_type(4)));
typedef unsigned int u32x2 __attribute__((ext_vector_type(2)));

__device__ __forceinline__ float bf2f(__hip_bfloat16 v) { return __bfloat162float(v); }
__device__ __forceinline__ float bfbits(unsigned int lo16) {
  unsigned int u = lo16 << 16;
  float f;
  memcpy(&f, &u, 4);
  return f;
}
__device__ __forceinline__ unsigned int packbf2(float x, float y) {
  __hip_bfloat16 bx = __float2bfloat16(x), by = __float2bfloat16(y);
  unsigned short ux, uy;
  memcpy(&ux, &bx, 2);
  memcpy(&uy, &by, 2);
  return (unsigned int)ux | ((unsigned int)uy << 16);
}

// flag-driven generic accessors: fbf=1 -> floats stored as bf16; i64=1 -> ints stored as int64
__device__ __forceinline__ float loadF(const void* p, long i, int fbf) {
  return fbf ? bf2f(((const __hip_bfloat16*)p)[i]) : ((const float*)p)[i];
}
__device__ __forceinline__ void storeF(void* p, long i, float v, int fbf) {
  if (fbf) ((__hip_bfloat16*)p)[i] = __float2bfloat16(v);
  else ((float*)p)[i] = v;
}
__device__ __forceinline__ int loadI(const void* p, long i, int i64) {
  return i64 ? (int)((const long long*)p)[i] : ((const int*)p)[i];
}

__global__ void k_detect(const void* x, const void* ei, int* flags) {
  __shared__ int s_f32sig, s_i32sig;
  if (threadIdx.x == 0) { s_f32sig = 0; s_i32sig = 0; }
  __syncthreads();
  int t = threadIdx.x;
  const unsigned short* u = (const unsigned short*)x;
  int f = 0;
  for (int i = 2 * t; i < 8192; i += 512) if (u[i] >= 0x4000) f = 1;
  const unsigned int* w = (const unsigned int*)ei;
  int g = 0;
  for (int i = 2 * t + 1; i < 8192; i += 512) if (w[i] != 0u) g = 1;
  if (f) atomicOr(&s_f32sig, 1);
  if (g) atomicOr(&s_i32sig, 1);
  __syncthreads();
  if (t == 0) { flags[0] = s_f32sig ? 0 : 1; flags[1] = s_i32sig ? 0 : 1; }
}

__global__ void k_zero(int* __restrict__ p, int n) {
  int i = blockIdx.x * blockDim.x + threadIdx.x;
  int stride = gridDim.x * blockDim.x;
  for (; i < n; i += stride) p[i] = 0;
}

// fused colsum + bf16 conversion; output is SLICE-MAJOR xs[4][NN][32cols]
// (64B contiguous per node per slice -> pure L2 lines for the sharded gather).
// block 256 = 16 rows x 16 col-groups; per-thread 8-col f32 partials -> LDS -> 128 atomics.
__global__ __launch_bounds__(256) void k_prep(
    const void* __restrict__ x, __hip_bfloat16* __restrict__ xs,
    float* __restrict__ colsum, const int* __restrict__ flags) {
  int fbf = flags[0];
  int t = threadIdx.x;
  int lane16 = t & 15;   // col group: cols [8*lane16, 8*lane16+8)
  int rowoff = t >> 4;   // 0..15
  float acc[8] = {};
  for (int r = blockIdx.x * 16 + rowoff; r < NN; r += gridDim.x * 16) {
    uint4 o;
    if (fbf) {
      uint4 v = ((const uint4*)x)[(long)r * 16 + lane16];
      acc[0] += bfbits(v.x & 0xffffu); acc[1] += bfbits(v.x >> 16);
      acc[2] += bfbits(v.y & 0xffffu); acc[3] += bfbits(v.y >> 16);
      acc[4] += bfbits(v.z & 0xffffu); acc[5] += bfbits(v.z >> 16);
      acc[6] += bfbits(v.w & 0xffffu); acc[7] += bfbits(v.w >> 16);
      o = v;  // already bf16 bits
    } else {
      float4 a = ((const float4*)x)[(long)r * 32 + lane16 * 2];
      float4 b = ((const float4*)x)[(long)r * 32 + lane16 * 2 + 1];
      acc[0] += a.x; acc[1] += a.y; acc[2] += a.z; acc[3] += a.w;
      acc[4] += b.x; acc[5] += b.y; acc[6] += b.z; acc[7] += b.w;
      o.x = packbf2(a.x, a.y); o.y = packbf2(a.z, a.w);
      o.z = packbf2(b.x, b.y); o.w = packbf2(b.z, b.w);
    }
    // slice-major: slice = lane16>>2 (32 cols), within-slice uint4 = lane16&3
    ((uint4*)xs)[((long)(lane16 >> 2) * NN + r) * 4 + (lane16 & 3)] = o;
  }
  __shared__ float s[16][DIN];
#pragma unroll
  for (int k = 0; k < 8; ++k) s[rowoff][lane16 * 8 + k] = acc[k];
  __syncthreads();
  if (t < DIN) {
    float v = 0.f;
#pragma unroll
    for (int ro = 0; ro < 16; ++ro) v += s[ro][t];
    atomicAdd(&colsum[t], v);
  }
}

__global__ void k_handcrafted(const float* __restrict__ colsum, void* __restrict__ out,
                              const int* __restrict__ flags) {
  __shared__ float s[DIN];
  int fbf = flags[0];
  int t = threadIdx.x;
  s[t] = colsum[t];
  __syncthreads();
  for (int off = DIN / 2; off > 0; off >>= 1) {
    if (t < off) s[t] += s[t + off];
    __syncthreads();
  }
  float g = s[0];
  storeF(out, NG * DH + t, colsum[t] / g, fbf);
  if (t == 0) storeF(out, NG * DH + DIN, logf(g), fbf);
}

// pack weights into MFMA b-frag order:
// pack[m*K*DH + ((ct*KS + ks)*64 + l)*8 + j] = W_m[(ks*32 + (l>>4)*8 + j)*DH + ct*16 + (l&15)]
__global__ void k_pack_w(const void* __restrict__ Wrel, const void* __restrict__ Wroot,
                         const void* __restrict__ bias, __hip_bfloat16* __restrict__ pack,
                         float* __restrict__ biasf, const int* __restrict__ flags, int K) {
  int fbf = flags[0];
  int KS = K >> 5;
  int total = 2 * K * DH;
  int i = blockIdx.x * blockDim.x + threadIdx.x;
  int stride = gridDim.x * blockDim.x;
  for (int p = i; p < total; p += stride) {
    int m = p / (K * DH);
    int r = p % (K * DH);
    int j = r & 7;
    int l = (r >> 3) & 63;
    int q2 = r >> 9;       // ct*KS + ks
    int ks = q2 % KS;
    int ct = q2 / KS;
    int kk = ks * 32 + (l >> 4) * 8 + j;
    int col = ct * 16 + (l & 15);
    const void* W = m ? Wroot : Wrel;
    pack[p] = __float2bfloat16(loadF(W, (long)kk * DH + col, fbf));
  }
  if (i < DH) biasf[i] = loadF(bias, i, fbf);
}

// ---------- CSR build ----------
__global__ void k_deg(const void* __restrict__ ei, int* __restrict__ cnt,
                      const int* __restrict__ flags) {
  int i64 = flags[1];
  int e = blockIdx.x * blockDim.x + threadIdx.x;
  int stride = gridDim.x * blockDim.x;
  for (; e < NE; e += stride) {
    int d = loadI(ei, (long)NE + e, i64);
    d = min(max(d, 0), NN - 1);
    atomicAdd(&cnt[d], 1);
  }
}

#define SCAN_B 256
__global__ void k_scan1(const int* __restrict__ cnt, int* __restrict__ rowptr,
                        int* __restrict__ bsum) {
  __shared__ int s[SCAN_B];
  int b = blockIdx.x, t = threadIdx.x;
  int i = b * SCAN_B + t;
  int v = (i < NN) ? cnt[i] : 0;
  s[t] = v;
  __syncthreads();
  for (int off = 1; off < SCAN_B; off <<= 1) {
    int xv = (t >= off) ? s[t - off] : 0;
    __syncthreads();
    s[t] += xv;
    __syncthreads();
  }
  if (i < NN) rowptr[i] = s[t] - v;
  if (t == SCAN_B - 1) bsum[b] = s[t];
}

__global__ void k_scan2(int* __restrict__ bsum, int nb) {
  __shared__ int s[SCAN_B];
  int t = threadIdx.x;
  int v = (t < nb) ? bsum[t] : 0;
  s[t] = v;
  __syncthreads();
  for (int off = 1; off < SCAN_B; off <<= 1) {
    int xv = (t >= off) ? s[t - off] : 0;
    __syncthreads();
    s[t] += xv;
    __syncthreads();
  }
  if (t < nb) bsum[t] = s[t] - v;  // exclusive
}

__global__ void k_scan3(int* __restrict__ rowptr, const int* __restrict__ bsum) {
  int i = blockIdx.x * blockDim.x + threadIdx.x;
  int stride = gridDim.x * blockDim.x;
  for (; i < NN; i += stride) rowptr[i] += bsum[i >> 8];
  if (blockIdx.x == 0 && threadIdx.x == 0) rowptr[NN] = NE;
}

__global__ void k_fill(const void* __restrict__ ei, const int* __restrict__ rowptr,
                       int* __restrict__ cur, int* __restrict__ srcs,
                       const int* __restrict__ flags) {
  int i64 = flags[1];
  int e = blockIdx.x * blockDim.x + threadIdx.x;
  int stride = gridDim.x * blockDim.x;
  for (; e < NE; e += stride) {
    int s = loadI(ei, e, i64);
    int d = loadI(ei, (long)NE + e, i64);
    s = min(max(s, 0), NN - 1);
    d = min(max(d, 0), NN - 1);
    int p = atomicAdd(&cur[d], 1);
    srcs[rowptr[d] + p] = s;
  }
}

// ---------- XCD-sharded gather over SLICE-MAJOR h ----------
// hs layout: [SL][NN][64B] with SL = K/32 slices of 32 cols. Each slice is a
// contiguous 3.2MB region of pure 128B lines; role = blockIdx.x & 7 -> XCD
// (round-robin dispatch) so per-XCD working set = one slice < 4MiB L2.
// Engine: lane = (node, col). Wave = 8 nodes x 8 cols (u32x2 = 8B = 4 bf16).
// Each lane serially accumulates its 4 columns over its node's edge list,
// unrolled x4. NO shuffles, no cross-lane reduction.
// K=256: role = slice. K=128: 4 slices x 2 node-halves (role = s*2 + half).
template <int K>
__global__ __launch_bounds__(256) void k_gathers(
    const int* __restrict__ rowptr, const int* __restrict__ srcs,
    const __hip_bfloat16* __restrict__ hs, __hip_bfloat16* __restrict__ agg) {
  constexpr int SL = K / 32;
  constexpr int HALVES = 8 / SL;
  constexpr int NPH = (NN + HALVES - 1) / HALVES;
  int role = blockIdx.x & 7;
  int nb = blockIdx.x >> 3;
  int s = role / HALVES;
  int half = role % HALVES;
  int t = threadIdx.x;
  int nsub = t >> 3;  // 0..31: node within block
  int c = t & 7;      // u32x2 within 64B slice row
  int node = half * NPH + nb * 32 + nsub;
  int nlim = min((half + 1) * NPH, NN);
  if (node >= nlim) return;
  const u32x2* h2 = (const u32x2*)hs;
  u32x2* agg2 = (u32x2*)agg;
  long sbase = (long)s * NN;
  int beg = rowptr[node], end = rowptr[node + 1];
  float a0 = 0.f, a1 = 0.f, a2 = 0.f, a3 = 0.f;
  int i = beg;
  for (; i + 3 < end; i += 4) {
    int s0 = __builtin_nontemporal_load(&srcs[i]);
    int s1 = __builtin_nontemporal_load(&srcs[i + 1]);
    int s2 = __builtin_nontemporal_load(&srcs[i + 2]);
    int s3 = __builtin_nontemporal_load(&srcs[i + 3]);
    u32x2 v0 = h2[(sbase + s0) * 8 + c];
    u32x2 v1 = h2[(sbase + s1) * 8 + c];
    u32x2 v2 = h2[(sbase + s2) * 8 + c];
    u32x2 v3 = h2[(sbase + s3) * 8 + c];
    a0 += bfbits(v0.x & 0xffffu) + bfbits(v1.x & 0xffffu) +
          bfbits(v2.x & 0xffffu) + bfbits(v3.x & 0xffffu);
    a1 += bfbits(v0.x >> 16) + bfbits(v1.x >> 16) +
          bfbits(v2.x >> 16) + bfbits(v3.x >> 16);
    a2 += bfbits(v0.y & 0xffffu) + bfbits(v1.y & 0xffffu) +
          bfbits(v2.y & 0xffffu) + bfbits(v3.y & 0xffffu);
    a3 += bfbits(v0.y >> 16) + bfbits(v1.y >> 16) +
          bfbits(v2.y >> 16) + bfbits(v3.y >> 16);
  }
  for (; i < end; ++i) {
    int s0 = __builtin_nontemporal_load(&srcs[i]);
    u32x2 v0 = h2[(sbase + s0) * 8 + c];
    a0 += bfbits(v0.x & 0xffffu);
    a1 += bfbits(v0.x >> 16);
    a2 += bfbits(v0.y & 0xffffu);
    a3 += bfbits(v0.y >> 16);
  }
  u32x2 o;
  o.x = packbf2(a0, a1);
  o.y = packbf2(a2, a3);
  __builtin_nontemporal_store(o, &agg2[(long)node * (K / 4) + s * 8 + c]);
}

// out[n][:] = relu(A1[n][:] @ Wrel + A2[n][:] @ Wroot + bias)
// A1 node-major (gather output). A2 SLICE-MAJOR [K/32][NN][32cols]: each bf16x8
// fragment (kofs=ks*32+q*8) sits inside slice ks at offset q*8. OUTS=true ->
// write slice-major [8][NN][32cols] (feeds next gather); else node-major (pool).
template <int K, bool OUTS>
__global__ __launch_bounds__(256, 4) void k_gemm(
    const __hip_bfloat16* __restrict__ A1, const __hip_bfloat16* __restrict__ A2,
    const __hip_bfloat16* __restrict__ Wpack, const float* __restrict__ bias,
    __hip_bfloat16* __restrict__ out) {
  constexpr int KS = K >> 5;
  int lane = threadIdx.x & 63;
  int wave = threadIdx.x >> 6;
  int m15 = lane & 15;
  int q = lane >> 4;
  int row0 = blockIdx.x * 32;
  const short* A1s = (const short*)A1;
  const short* A2s = (const short*)A2;
  const short* Wp = (const short*)Wpack;
  const int wrootOfs = K * DH;  // elems: second packed matrix
  f32x4 acc[2][4] = {};
#pragma unroll
  for (int ks = 0; ks < KS; ++ks) {
    int kofs = ks * 32 + q * 8;
    bf16x8 a1[2], a2[2], b1[4], b2[4];
#pragma unroll
    for (int mt = 0; mt < 2; ++mt) {
      int r = row0 + mt * 16 + m15;
      if (r > NN - 1) r = NN - 1;
      a1[mt] = *(const bf16x8*)(A1s + (long)r * K + kofs);
      // slice-major A2: ((ks*NN + r)*32 + q*8)   [valid for K=128 and K=256]
      a2[mt] = *(const bf16x8*)(A2s + ((long)ks * NN + r) * 32 + q * 8);
    }
#pragma unroll
    for (int ct = 0; ct < 4; ++ct) {
      int gct = wave * 4 + ct;
      const short* base = Wp + ((gct * KS + ks) * 64 + lane) * 8;
      b1[ct] = *(const bf16x8*)(base);
      b2[ct] = *(const bf16x8*)(base + wrootOfs);
    }
#pragma unroll
    for (int mt = 0; mt < 2; ++mt)
#pragma unroll
      for (int ct = 0; ct < 4; ++ct) {
        acc[mt][ct] = __builtin_amdgcn_mfma_f32_16x16x32_bf16(a1[mt], b1[ct], acc[mt][ct], 0, 0, 0);
        acc[mt][ct] = __builtin_amdgcn_mfma_f32_16x16x32_bf16(a2[mt], b2[ct], acc[mt][ct], 0, 0, 0);
      }
  }
#pragma unroll
  for (int mt = 0; mt < 2; ++mt)
#pragma unroll
    for (int ct = 0; ct < 4; ++ct) {
      int col = (wave * 4 + ct) * 16 + m15;
      float bv = bias[col];
#pragma unroll
      for (int r = 0; r < 4; ++r) {
        int row = row0 + mt * 16 + q * 4 + r;
        if (row < NN) {
          float v = acc[mt][ct][r] + bv;
          long oidx = OUTS ? (((long)(col >> 5) * NN + row) * 32 + (col & 31))
                           : ((long)row * DH + col);
          out[oidx] = __float2bfloat16(fmaxf(v, 0.f));
        }
      }
    }
}

// ---------- pooling (batch is sorted -> segment bounds, no big atomics) ----------
__global__ void k_bounds(const void* __restrict__ batch, int* __restrict__ gstart,
                         int* __restrict__ gend, const int* __restrict__ flags) {
  int i64 = flags[1];
  int n = blockIdx.x * blockDim.x + threadIdx.x;
  if (n >= NN) return;
  int b = min(max(loadI(batch, n, i64), 0), NG - 1);
  int bp = (n == 0) ? -1 : min(max(loadI(batch, n - 1, i64), 0), NG - 1);
  if (b != bp) gstart[b] = n;
  int bn = (n == NN - 1) ? -1 : min(max(loadI(batch, n + 1, i64), 0), NG - 1);
  if (b != bn) gend[b] = n + 1;
}

// grid (NG, PSPLIT), block 128: each block partial-sums a slice of the graph's rows
__global__ void k_poolpart(const int* __restrict__ gstart, const int* __restrict__ gend,
                           const __hip_bfloat16* __restrict__ h, float* __restrict__ pooled) {
  int g = blockIdx.x;
  int p = blockIdx.y;
  int j = threadIdx.x;  // 0..127, 2 cols each
  int s = gstart[g], e = gend[g];
  int len = e - s;
  if (len <= 0) return;
  int chunk = (len + PSPLIT - 1) / PSPLIT;
  int rs = s + p * chunk;
  int re = min(rs + chunk, e);
  if (rs >= re) return;
  const unsigned int* h2 = (const unsigned int*)h;  // 128 uints per row
  float a0 = 0.f, a1 = 0.f;
  for (int r = rs; r < re; ++r) {
    unsigned int v = h2[(long)r * 128 + j];
    a0 += bfbits(v & 0xffffu);
    a1 += bfbits(v >> 16);
  }
  atomicAdd(&pooled[g * DH + 2 * j], a0);
  atomicAdd(&pooled[g * DH + 2 * j + 1], a1);
}

__global__ void k_poolfin(const int* __restrict__ gstart, const int* __restrict__ gend,
                          const float* __restrict__ pooled, void* __restrict__ out,
                          const int* __restrict__ flags) {
  int fbf = flags[0];
  int g = blockIdx.x;
  int j = threadIdx.x;
  float cnt = fmaxf((float)(gend[g] - gstart[g]), 1.0f);
  storeF(out, (long)g * DH + j, pooled[g * DH + j] / cnt, fbf);
}

extern "C" void kernel_launch(void* const* d_in, const int* in_sizes, int n_in,
                              void* d_out, int out_size, void* d_ws, size_t ws_size,
                              hipStream_t stream) {
  const void* x = d_in[0];
  const void* ei = d_in[1];
  const void* batch = d_in[2];
  const void* W1r = d_in[3];
  const void* W1o = d_in[4];
  const void* b1 = d_in[5];
  const void* W2r = d_in[6];
  const void* W2o = d_in[7];
  const void* b2 = d_in[8];
  void* out = d_out;

  // ---- workspace layout (256B-aligned chunks) ----
  char* w = (char*)d_ws;
  auto alloc = [&](size_t bytes) -> char* {
    char* p = w;
    w += (bytes + 255) & ~(size_t)255;
    return p;
  };
  int* flags = (int*)alloc(64);
  // contiguous zero region: cnt, cur, colsum, gstart, gend, pooled
  const int zero_n = NN + NN + DIN + NG + NG + NG * DH;
  int* zreg = (int*)alloc((size_t)zero_n * 4);
  int* cnt = zreg;
  int* cur = cnt + NN;
  float* colsum = (float*)(cur + NN);
  int* gstart = (int*)(colsum + DIN);
  int* gend = gstart + NG;
  float* pooled = (float*)(gend + NG);
  int* rowptr = (int*)alloc((NN + 1) * 4);
  int* bsum = (int*)alloc(SCAN_B * 4);
  int* srcs = (int*)alloc((size_t)NE * 4);
  __hip_bfloat16* xs = (__hip_bfloat16*)alloc((size_t)NN * DIN * 2);    // slice-major x
  __hip_bfloat16* aggb = (__hip_bfloat16*)alloc((size_t)NN * DH * 2);   // node-major agg
  __hip_bfloat16* h1s = (__hip_bfloat16*)alloc((size_t)NN * DH * 2);    // slice-major h1 / node-major h3
  __hip_bfloat16* h2s = (__hip_bfloat16*)alloc((size_t)NN * DH * 2);    // slice-major h2
  __hip_bfloat16* wp1 = (__hip_bfloat16*)alloc((size_t)2 * DIN * DH * 2);
  __hip_bfloat16* wp2 = (__hip_bfloat16*)alloc((size_t)2 * DH * DH * 2);
  float* b1f = (float*)alloc(DH * 4);
  float* b2f = (float*)alloc(DH * 4);
  __hip_bfloat16* hA = h1s;  // layer-3 node-major output aliases h1s (dead after gemm2)

  const int nblk = (NN + SCAN_B - 1) / SCAN_B;       // 196
  const int gemm_grid = (NN + 31) / 32;              // 1563
  const int g256_grid = 8 * ((NN + 31) / 32);        // 8 roles x 1563 (32 nodes/block)
  const int g128_grid = 8 * ((NN / 2 + 31) / 32);    // 8 roles x 782 (4 slices x 2 halves)

  k_detect<<<1, 256, 0, stream>>>(x, ei, flags);
  k_zero<<<512, 256, 0, stream>>>(zreg, zero_n);

  // weight packing + fused colsum/convert + handcrafted head
  k_pack_w<<<64, 256, 0, stream>>>(W1r, W1o, b1, wp1, b1f, flags, DIN);
  k_pack_w<<<128, 256, 0, stream>>>(W2r, W2o, b2, wp2, b2f, flags, DH);
  k_prep<<<1024, 256, 0, stream>>>(x, xs, colsum, flags);
  k_handcrafted<<<1, 128, 0, stream>>>(colsum, out, flags);

  // CSR build (once; reused by all 3 layers)
  k_deg<<<1024, 256, 0, stream>>>(ei, cnt, flags);
  k_scan1<<<nblk, SCAN_B, 0, stream>>>(cnt, rowptr, bsum);
  k_scan2<<<1, SCAN_B, 0, stream>>>(bsum, nblk);
  k_scan3<<<256, 256, 0, stream>>>(rowptr, bsum);
  k_fill<<<1024, 256, 0, stream>>>(ei, rowptr, cur, srcs, flags);

  // layer 1 (K = 128): xs -> aggb -> h1s (slice-major)
  k_gathers<DIN><<<g128_grid, 256, 0, stream>>>(rowptr, srcs, xs, aggb);
  k_gemm<DIN, true><<<gemm_grid, 256, 0, stream>>>(aggb, xs, wp1, b1f, h1s);
  // layer 2 (K = 256): h1s -> aggb -> h2s (slice-major)
  k_gathers<DH><<<g256_grid, 256, 0, stream>>>(rowptr, srcs, h1s, aggb);
  k_gemm<DH, true><<<gemm_grid, 256, 0, stream>>>(aggb, h1s, wp2, b2f, h2s);
  // layer 3 (K = 256, shared weights): h2s -> aggb -> hA (node-major, for pool)
  k_gathers<DH><<<g256_grid, 256, 0, stream>>>(rowptr, srcs, h2s, aggb);
  k_gemm<DH, false><<<gemm_grid, 256, 0, stream>>>(aggb, h2s, wp2, b2f, hA);

  // mean pool: segment bounds (batch sorted) + split partial sums + finalize
  k_bounds<<<nblk, 256, 0, stream>>>(batch, gstart, gend, flags);
  k_poolpart<<<dim3(NG, PSPLIT), 128, 0, stream>>>(gstart, gend, hA, pooled);
  k_poolfin<<<NG, DH, 0, stream>>>(gstart, gend, pooled, out, flags);
}

// Round 5
// 516.588 us; speedup vs baseline: 1.7436x; 1.1351x over previous
//
#include <hip/hip_runtime.h>
#include <hip/hip_bf16.h>
#include <string.h>

#define NN 50000
#define NE 800000
#define DIN 128
#define DH 256
#define NG 64
#define PSPLIT 32
#define GCAP 3072

typedef short bf16x8 __attribute__((ext_vector_type(8)));
typedef float f32x4 __attribute__((ext_vector_type(4)));
typedef unsigned int u32x2 __attribute__((ext_vector_type(2)));

__device__ __forceinline__ float bf2f(__hip_bfloat16 v) { return __bfloat162float(v); }
__device__ __forceinline__ float bfbits(unsigned int lo16) {
  unsigned int u = lo16 << 16;
  float f;
  memcpy(&f, &u, 4);
  return f;
}
__device__ __forceinline__ unsigned int packbf2(float x, float y) {
  __hip_bfloat16 bx = __float2bfloat16(x), by = __float2bfloat16(y);
  unsigned short ux, uy;
  memcpy(&ux, &bx, 2);
  memcpy(&uy, &by, 2);
  return (unsigned int)ux | ((unsigned int)uy << 16);
}

// flag-driven generic accessors: fbf=1 -> floats stored as bf16; i64=1 -> ints stored as int64
__device__ __forceinline__ float loadF(const void* p, long i, int fbf) {
  return fbf ? bf2f(((const __hip_bfloat16*)p)[i]) : ((const float*)p)[i];
}
__device__ __forceinline__ void storeF(void* p, long i, float v, int fbf) {
  if (fbf) ((__hip_bfloat16*)p)[i] = __float2bfloat16(v);
  else ((float*)p)[i] = v;
}
__device__ __forceinline__ int loadI(const void* p, long i, int i64) {
  return i64 ? (int)((const long long*)p)[i] : ((const int*)p)[i];
}

__global__ void k_detect(const void* x, const void* ei, int* flags) {
  __shared__ int s_f32sig, s_i32sig;
  if (threadIdx.x == 0) { s_f32sig = 0; s_i32sig = 0; }
  __syncthreads();
  int t = threadIdx.x;
  const unsigned short* u = (const unsigned short*)x;
  int f = 0;
  for (int i = 2 * t; i < 8192; i += 512) if (u[i] >= 0x4000) f = 1;
  const unsigned int* w = (const unsigned int*)ei;
  int g = 0;
  for (int i = 2 * t + 1; i < 8192; i += 512) if (w[i] != 0u) g = 1;
  if (f) atomicOr(&s_f32sig, 1);
  if (g) atomicOr(&s_i32sig, 1);
  __syncthreads();
  if (t == 0) { flags[0] = s_f32sig ? 0 : 1; flags[1] = s_i32sig ? 0 : 1; }
}

__global__ void k_zero(int* __restrict__ p, int n) {
  int i = blockIdx.x * blockDim.x + threadIdx.x;
  int stride = gridDim.x * blockDim.x;
  for (; i < n; i += stride) p[i] = 0;
}

// fused colsum + bf16 conversion; output is SLICE-MAJOR xs[4][NN][32cols]
// (64B contiguous per node per slice -> pure L2 lines for the sharded gather).
// block 256 = 16 rows x 16 col-groups; per-thread 8-col f32 partials -> LDS -> 128 atomics.
__global__ __launch_bounds__(256) void k_prep(
    const void* __restrict__ x, __hip_bfloat16* __restrict__ xs,
    float* __restrict__ colsum, const int* __restrict__ flags) {
  int fbf = flags[0];
  int t = threadIdx.x;
  int lane16 = t & 15;   // col group: cols [8*lane16, 8*lane16+8)
  int rowoff = t >> 4;   // 0..15
  float acc[8] = {};
  for (int r = blockIdx.x * 16 + rowoff; r < NN; r += gridDim.x * 16) {
    uint4 o;
    if (fbf) {
      uint4 v = ((const uint4*)x)[(long)r * 16 + lane16];
      acc[0] += bfbits(v.x & 0xffffu); acc[1] += bfbits(v.x >> 16);
      acc[2] += bfbits(v.y & 0xffffu); acc[3] += bfbits(v.y >> 16);
      acc[4] += bfbits(v.z & 0xffffu); acc[5] += bfbits(v.z >> 16);
      acc[6] += bfbits(v.w & 0xffffu); acc[7] += bfbits(v.w >> 16);
      o = v;  // already bf16 bits
    } else {
      float4 a = ((const float4*)x)[(long)r * 32 + lane16 * 2];
      float4 b = ((const float4*)x)[(long)r * 32 + lane16 * 2 + 1];
      acc[0] += a.x; acc[1] += a.y; acc[2] += a.z; acc[3] += a.w;
      acc[4] += b.x; acc[5] += b.y; acc[6] += b.z; acc[7] += b.w;
      o.x = packbf2(a.x, a.y); o.y = packbf2(a.z, a.w);
      o.z = packbf2(b.x, b.y); o.w = packbf2(b.z, b.w);
    }
    // slice-major: slice = lane16>>2 (32 cols), within-slice uint4 = lane16&3
    ((uint4*)xs)[((long)(lane16 >> 2) * NN + r) * 4 + (lane16 & 3)] = o;
  }
  __shared__ float s[16][DIN];
#pragma unroll
  for (int k = 0; k < 8; ++k) s[rowoff][lane16 * 8 + k] = acc[k];
  __syncthreads();
  if (t < DIN) {
    float v = 0.f;
#pragma unroll
    for (int ro = 0; ro < 16; ++ro) v += s[ro][t];
    atomicAdd(&colsum[t], v);
  }
}

__global__ void k_handcrafted(const float* __restrict__ colsum, void* __restrict__ out,
                              const int* __restrict__ flags) {
  __shared__ float s[DIN];
  int fbf = flags[0];
  int t = threadIdx.x;
  s[t] = colsum[t];
  __syncthreads();
  for (int off = DIN / 2; off > 0; off >>= 1) {
    if (t < off) s[t] += s[t + off];
    __syncthreads();
  }
  float g = s[0];
  storeF(out, NG * DH + t, colsum[t] / g, fbf);
  if (t == 0) storeF(out, NG * DH + DIN, logf(g), fbf);
}

// pack weights into MFMA b-frag order:
// pack[m*K*DH + ((ct*KS + ks)*64 + l)*8 + j] = W_m[(ks*32 + (l>>4)*8 + j)*DH + ct*16 + (l&15)]
__global__ void k_pack_w(const void* __restrict__ Wrel, const void* __restrict__ Wroot,
                         const void* __restrict__ bias, __hip_bfloat16* __restrict__ pack,
                         float* __restrict__ biasf, const int* __restrict__ flags, int K) {
  int fbf = flags[0];
  int KS = K >> 5;
  int total = 2 * K * DH;
  int i = blockIdx.x * blockDim.x + threadIdx.x;
  int stride = gridDim.x * blockDim.x;
  for (int p = i; p < total; p += stride) {
    int m = p / (K * DH);
    int r = p % (K * DH);
    int j = r & 7;
    int l = (r >> 3) & 63;
    int q2 = r >> 9;       // ct*KS + ks
    int ks = q2 % KS;
    int ct = q2 / KS;
    int kk = ks * 32 + (l >> 4) * 8 + j;
    int col = ct * 16 + (l & 15);
    const void* W = m ? Wroot : Wrel;
    pack[p] = __float2bfloat16(loadF(W, (long)kk * DH + col, fbf));
  }
  if (i < DH) biasf[i] = loadF(bias, i, fbf);
}

// ---------- CSR build ----------
__global__ void k_deg(const void* __restrict__ ei, int* __restrict__ cnt,
                      const int* __restrict__ flags) {
  int i64 = flags[1];
  int e = blockIdx.x * blockDim.x + threadIdx.x;
  int stride = gridDim.x * blockDim.x;
  for (; e < NE; e += stride) {
    int d = loadI(ei, (long)NE + e, i64);
    d = min(max(d, 0), NN - 1);
    atomicAdd(&cnt[d], 1);
  }
}

#define SCAN_B 256
__global__ void k_scan1(const int* __restrict__ cnt, int* __restrict__ rowptr,
                        int* __restrict__ bsum) {
  __shared__ int s[SCAN_B];
  int b = blockIdx.x, t = threadIdx.x;
  int i = b * SCAN_B + t;
  int v = (i < NN) ? cnt[i] : 0;
  s[t] = v;
  __syncthreads();
  for (int off = 1; off < SCAN_B; off <<= 1) {
    int xv = (t >= off) ? s[t - off] : 0;
    __syncthreads();
    s[t] += xv;
    __syncthreads();
  }
  if (i < NN) rowptr[i] = s[t] - v;
  if (t == SCAN_B - 1) bsum[b] = s[t];
}

__global__ void k_scan2(int* __restrict__ bsum, int nb) {
  __shared__ int s[SCAN_B];
  int t = threadIdx.x;
  int v = (t < nb) ? bsum[t] : 0;
  s[t] = v;
  __syncthreads();
  for (int off = 1; off < SCAN_B; off <<= 1) {
    int xv = (t >= off) ? s[t - off] : 0;
    __syncthreads();
    s[t] += xv;
    __syncthreads();
  }
  if (t < nb) bsum[t] = s[t] - v;  // exclusive
}

__global__ void k_scan3(int* __restrict__ rowptr, const int* __restrict__ bsum) {
  int i = blockIdx.x * blockDim.x + threadIdx.x;
  int stride = gridDim.x * blockDim.x;
  for (; i < NN; i += stride) rowptr[i] += bsum[i >> 8];
  if (blockIdx.x == 0 && threadIdx.x == 0) rowptr[NN] = NE;
}

__global__ void k_fill(const void* __restrict__ ei, const int* __restrict__ rowptr,
                       int* __restrict__ cur, int* __restrict__ srcs,
                       const int* __restrict__ flags) {
  int i64 = flags[1];
  int e = blockIdx.x * blockDim.x + threadIdx.x;
  int stride = gridDim.x * blockDim.x;
  for (; e < NE; e += stride) {
    int s = loadI(ei, e, i64);
    int d = loadI(ei, (long)NE + e, i64);
    s = min(max(s, 0), NN - 1);
    d = min(max(d, 0), NN - 1);
    int p = atomicAdd(&cur[d], 1);
    srcs[rowptr[d] + p] = s;
  }
}

// ---------- XCD-sharded gather over SLICE-MAJOR h ----------
// hs layout: [SL][NN][64B], SL = K/32 slices of 32 cols; role = blockIdx.x & 7
// -> XCD (round-robin dispatch), per-XCD working set = one 3.2MB slice < 4MiB L2.
// Engine: block = 32 adjacent nodes -> ONE contiguous srcs window, staged in LDS
// (removes HBM srcs latency from the per-edge chain). lane = (node, col-pair);
// masked 8-wide inner loop: 8 independent h loads in flight, fmaf-masked slots,
// NO tail loop, NO shuffles.
template <int K>
__global__ __launch_bounds__(256) void k_gathers(
    const int* __restrict__ rowptr, const int* __restrict__ srcs,
    const __hip_bfloat16* __restrict__ hs, __hip_bfloat16* __restrict__ agg) {
  constexpr int SL = K / 32;
  constexpr int HALVES = 8 / SL;
  constexpr int NPH = (NN + HALVES - 1) / HALVES;
  __shared__ int se[GCAP];
  __shared__ int sb[2];
  int role = blockIdx.x & 7;
  int nb = blockIdx.x >> 3;
  int s = role / HALVES;
  int half = role % HALVES;
  int t = threadIdx.x;
  int n0 = half * NPH + nb * 32;
  int nlim = min((half + 1) * NPH, NN);
  if (t == 0) {
    sb[0] = rowptr[n0];
    sb[1] = rowptr[min(n0 + 32, nlim)];
  }
  __syncthreads();
  int wbeg = sb[0];
  int wlen = min(sb[1] - wbeg, GCAP);
  for (int i = t; i < wlen; i += 256)
    se[i] = __builtin_nontemporal_load(&srcs[wbeg + i]);
  __syncthreads();
  int nsub = t >> 3;  // 0..31: node within block
  int c = t & 7;      // u32x2 (4 cols) within 64B slice row
  int node = n0 + nsub;
  if (node >= nlim) return;
  const u32x2* hb = (const u32x2*)hs + (long)s * NN * 8 + c;
  u32x2* agg2 = (u32x2*)agg;
  int beg = rowptr[node], end = rowptr[node + 1];
  float a0 = 0.f, a1 = 0.f, a2 = 0.f, a3 = 0.f;
  if (end - wbeg <= wlen) {
    // fast path: this node's edges fully staged in LDS
    int ib = beg - wbeg, ie = end - wbeg;
    for (int i = ib; i < ie; i += 8) {
      int idx[8];
      float m[8];
      u32x2 v[8];
#pragma unroll
      for (int u = 0; u < 8; ++u) {
        int j = i + u;
        int ok = j < ie;
        idx[u] = se[ok ? j : ib];
        m[u] = ok ? 1.f : 0.f;
      }
#pragma unroll
      for (int u = 0; u < 8; ++u) v[u] = hb[(long)idx[u] * 8];
#pragma unroll
      for (int u = 0; u < 8; ++u) {
        a0 = fmaf(m[u], bfbits(v[u].x & 0xffffu), a0);
        a1 = fmaf(m[u], bfbits(v[u].x >> 16), a1);
        a2 = fmaf(m[u], bfbits(v[u].y & 0xffffu), a2);
        a3 = fmaf(m[u], bfbits(v[u].y >> 16), a3);
      }
    }
  } else {
    // fallback (window > GCAP): identical loop straight from global srcs
    for (int i = beg; i < end; i += 8) {
      int idx[8];
      float m[8];
      u32x2 v[8];
#pragma unroll
      for (int u = 0; u < 8; ++u) {
        int j = i + u;
        int ok = j < end;
        idx[u] = __builtin_nontemporal_load(&srcs[ok ? j : beg]);
        m[u] = ok ? 1.f : 0.f;
      }
#pragma unroll
      for (int u = 0; u < 8; ++u) v[u] = hb[(long)idx[u] * 8];
#pragma unroll
      for (int u = 0; u < 8; ++u) {
        a0 = fmaf(m[u], bfbits(v[u].x & 0xffffu), a0);
        a1 = fmaf(m[u], bfbits(v[u].x >> 16), a1);
        a2 = fmaf(m[u], bfbits(v[u].y & 0xffffu), a2);
        a3 = fmaf(m[u], bfbits(v[u].y >> 16), a3);
      }
    }
  }
  u32x2 o;
  o.x = packbf2(a0, a1);
  o.y = packbf2(a2, a3);
  __builtin_nontemporal_store(o, &agg2[(long)node * (K / 4) + s * 8 + c]);
}

// out[n][:] = relu(A1[n][:] @ Wrel + A2[n][:] @ Wroot + bias)
// A1 node-major (gather output). A2 SLICE-MAJOR [K/32][NN][32cols]: each bf16x8
// fragment (kofs=ks*32+q*8) sits inside slice ks at offset q*8. OUTS=true ->
// write slice-major [8][NN][32cols] (feeds next gather); else node-major (pool).
template <int K, bool OUTS>
__global__ __launch_bounds__(256, 4) void k_gemm(
    const __hip_bfloat16* __restrict__ A1, const __hip_bfloat16* __restrict__ A2,
    const __hip_bfloat16* __restrict__ Wpack, const float* __restrict__ bias,
    __hip_bfloat16* __restrict__ out) {
  constexpr int KS = K >> 5;
  int lane = threadIdx.x & 63;
  int wave = threadIdx.x >> 6;
  int m15 = lane & 15;
  int q = lane >> 4;
  int row0 = blockIdx.x * 32;
  const short* A1s = (const short*)A1;
  const short* A2s = (const short*)A2;
  const short* Wp = (const short*)Wpack;
  const int wrootOfs = K * DH;  // elems: second packed matrix
  f32x4 acc[2][4] = {};
#pragma unroll
  for (int ks = 0; ks < KS; ++ks) {
    int kofs = ks * 32 + q * 8;
    bf16x8 a1[2], a2[2], b1[4], b2[4];
#pragma unroll
    for (int mt = 0; mt < 2; ++mt) {
      int r = row0 + mt * 16 + m15;
      if (r > NN - 1) r = NN - 1;
      a1[mt] = *(const bf16x8*)(A1s + (long)r * K + kofs);
      // slice-major A2: ((ks*NN + r)*32 + q*8)   [valid for K=128 and K=256]
      a2[mt] = *(const bf16x8*)(A2s + ((long)ks * NN + r) * 32 + q * 8);
    }
#pragma unroll
    for (int ct = 0; ct < 4; ++ct) {
      int gct = wave * 4 + ct;
      const short* base = Wp + ((gct * KS + ks) * 64 + lane) * 8;
      b1[ct] = *(const bf16x8*)(base);
      b2[ct] = *(const bf16x8*)(base + wrootOfs);
    }
#pragma unroll
    for (int mt = 0; mt < 2; ++mt)
#pragma unroll
      for (int ct = 0; ct < 4; ++ct) {
        acc[mt][ct] = __builtin_amdgcn_mfma_f32_16x16x32_bf16(a1[mt], b1[ct], acc[mt][ct], 0, 0, 0);
        acc[mt][ct] = __builtin_amdgcn_mfma_f32_16x16x32_bf16(a2[mt], b2[ct], acc[mt][ct], 0, 0, 0);
      }
  }
#pragma unroll
  for (int mt = 0; mt < 2; ++mt)
#pragma unroll
    for (int ct = 0; ct < 4; ++ct) {
      int col = (wave * 4 + ct) * 16 + m15;
      float bv = bias[col];
#pragma unroll
      for (int r = 0; r < 4; ++r) {
        int row = row0 + mt * 16 + q * 4 + r;
        if (row < NN) {
          float v = acc[mt][ct][r] + bv;
          long oidx = OUTS ? (((long)(col >> 5) * NN + row) * 32 + (col & 31))
                           : ((long)row * DH + col);
          out[oidx] = __float2bfloat16(fmaxf(v, 0.f));
        }
      }
    }
}

// ---------- pooling (batch is sorted -> segment bounds, no big atomics) ----------
__global__ void k_bounds(const void* __restrict__ batch, int* __restrict__ gstart,
                         int* __restrict__ gend, const int* __restrict__ flags) {
  int i64 = flags[1];
  int n = blockIdx.x * blockDim.x + threadIdx.x;
  if (n >= NN) return;
  int b = min(max(loadI(batch, n, i64), 0), NG - 1);
  int bp = (n == 0) ? -1 : min(max(loadI(batch, n - 1, i64), 0), NG - 1);
  if (b != bp) gstart[b] = n;
  int bn = (n == NN - 1) ? -1 : min(max(loadI(batch, n + 1, i64), 0), NG - 1);
  if (b != bn) gend[b] = n + 1;
}

// grid (NG, PSPLIT), block 128: each block partial-sums a slice of the graph's rows
__global__ void k_poolpart(const int* __restrict__ gstart, const int* __restrict__ gend,
                           const __hip_bfloat16* __restrict__ h, float* __restrict__ pooled) {
  int g = blockIdx.x;
  int p = blockIdx.y;
  int j = threadIdx.x;  // 0..127, 2 cols each
  int s = gstart[g], e = gend[g];
  int len = e - s;
  if (len <= 0) return;
  int chunk = (len + PSPLIT - 1) / PSPLIT;
  int rs = s + p * chunk;
  int re = min(rs + chunk, e);
  if (rs >= re) return;
  const unsigned int* h2 = (const unsigned int*)h;  // 128 uints per row
  float a0 = 0.f, a1 = 0.f;
  for (int r = rs; r < re; ++r) {
    unsigned int v = h2[(long)r * 128 + j];
    a0 += bfbits(v & 0xffffu);
    a1 += bfbits(v >> 16);
  }
  atomicAdd(&pooled[g * DH + 2 * j], a0);
  atomicAdd(&pooled[g * DH + 2 * j + 1], a1);
}

__global__ void k_poolfin(const int* __restrict__ gstart, const int* __restrict__ gend,
                          const float* __restrict__ pooled, void* __restrict__ out,
                          const int* __restrict__ flags) {
  int fbf = flags[0];
  int g = blockIdx.x;
  int j = threadIdx.x;
  float cnt = fmaxf((float)(gend[g] - gstart[g]), 1.0f);
  storeF(out, (long)g * DH + j, pooled[g * DH + j] / cnt, fbf);
}

extern "C" void kernel_launch(void* const* d_in, const int* in_sizes, int n_in,
                              void* d_out, int out_size, void* d_ws, size_t ws_size,
                              hipStream_t stream) {
  const void* x = d_in[0];
  const void* ei = d_in[1];
  const void* batch = d_in[2];
  const void* W1r = d_in[3];
  const void* W1o = d_in[4];
  const void* b1 = d_in[5];
  const void* W2r = d_in[6];
  const void* W2o = d_in[7];
  const void* b2 = d_in[8];
  void* out = d_out;

  // ---- workspace layout (256B-aligned chunks) ----
  char* w = (char*)d_ws;
  auto alloc = [&](size_t bytes) -> char* {
    char* p = w;
    w += (bytes + 255) & ~(size_t)255;
    return p;
  };
  int* flags = (int*)alloc(64);
  // contiguous zero region: cnt, cur, colsum, gstart, gend, pooled
  const int zero_n = NN + NN + DIN + NG + NG + NG * DH;
  int* zreg = (int*)alloc((size_t)zero_n * 4);
  int* cnt = zreg;
  int* cur = cnt + NN;
  float* colsum = (float*)(cur + NN);
  int* gstart = (int*)(colsum + DIN);
  int* gend = gstart + NG;
  float* pooled = (float*)(gend + NG);
  int* rowptr = (int*)alloc((NN + 1) * 4);
  int* bsum = (int*)alloc(SCAN_B * 4);
  int* srcs = (int*)alloc((size_t)NE * 4);
  __hip_bfloat16* xs = (__hip_bfloat16*)alloc((size_t)NN * DIN * 2);    // slice-major x
  __hip_bfloat16* aggb = (__hip_bfloat16*)alloc((size_t)NN * DH * 2);   // node-major agg
  __hip_bfloat16* h1s = (__hip_bfloat16*)alloc((size_t)NN * DH * 2);    // slice-major h1 / node-major h3
  __hip_bfloat16* h2s = (__hip_bfloat16*)alloc((size_t)NN * DH * 2);    // slice-major h2
  __hip_bfloat16* wp1 = (__hip_bfloat16*)alloc((size_t)2 * DIN * DH * 2);
  __hip_bfloat16* wp2 = (__hip_bfloat16*)alloc((size_t)2 * DH * DH * 2);
  float* b1f = (float*)alloc(DH * 4);
  float* b2f = (float*)alloc(DH * 4);
  __hip_bfloat16* hA = h1s;  // layer-3 node-major output aliases h1s (dead after gemm2)

  const int nblk = (NN + SCAN_B - 1) / SCAN_B;       // 196
  const int gemm_grid = (NN + 31) / 32;              // 1563
  const int g256_grid = 8 * ((NN + 31) / 32);        // 8 roles x 1563 (32 nodes/block)
  const int g128_grid = 8 * ((NN / 2 + 31) / 32);    // 8 roles x 782 (4 slices x 2 halves)

  k_detect<<<1, 256, 0, stream>>>(x, ei, flags);
  k_zero<<<512, 256, 0, stream>>>(zreg, zero_n);

  // weight packing + fused colsum/convert + handcrafted head
  k_pack_w<<<64, 256, 0, stream>>>(W1r, W1o, b1, wp1, b1f, flags, DIN);
  k_pack_w<<<128, 256, 0, stream>>>(W2r, W2o, b2, wp2, b2f, flags, DH);
  k_prep<<<1024, 256, 0, stream>>>(x, xs, colsum, flags);
  k_handcrafted<<<1, 128, 0, stream>>>(colsum, out, flags);

  // CSR build (once; reused by all 3 layers)
  k_deg<<<1024, 256, 0, stream>>>(ei, cnt, flags);
  k_scan1<<<nblk, SCAN_B, 0, stream>>>(cnt, rowptr, bsum);
  k_scan2<<<1, SCAN_B, 0, stream>>>(bsum, nblk);
  k_scan3<<<256, 256, 0, stream>>>(rowptr, bsum);
  k_fill<<<1024, 256, 0, stream>>>(ei, rowptr, cur, srcs, flags);

  // layer 1 (K = 128): xs -> aggb -> h1s (slice-major)
  k_gathers<DIN><<<g128_grid, 256, 0, stream>>>(rowptr, srcs, xs, aggb);
  k_gemm<DIN, true><<<gemm_grid, 256, 0, stream>>>(aggb, xs, wp1, b1f, h1s);
  // layer 2 (K = 256): h1s -> aggb -> h2s (slice-major)
  k_gathers<DH><<<g256_grid, 256, 0, stream>>>(rowptr, srcs, h1s, aggb);
  k_gemm<DH, true><<<gemm_grid, 256, 0, stream>>>(aggb, h1s, wp2, b2f, h2s);
  // layer 3 (K = 256, shared weights): h2s -> aggb -> hA (node-major, for pool)
  k_gathers<DH><<<g256_grid, 256, 0, stream>>>(rowptr, srcs, h2s, aggb);
  k_gemm<DH, false><<<gemm_grid, 256, 0, stream>>>(aggb, h2s, wp2, b2f, hA);

  // mean pool: segment bounds (batch sorted) + split partial sums + finalize
  k_bounds<<<nblk, 256, 0, stream>>>(batch, gstart, gend, flags);
  k_poolpart<<<dim3(NG, PSPLIT), 128, 0, stream>>>(gstart, gend, hA, pooled);
  k_poolfin<<<NG, DH, 0, stream>>>(gstart, gend, pooled, out, flags);
}